// Round 9
// baseline (292.219 us; speedup 1.0000x reference)
//
#include <hip/hip_runtime.h>
#include <math.h>

// LSTM fused: H=32, D=1, B=4096, T=1024 — R21: R20 + convoy-break + fmaf folds.
//
// Ledger at R20 (248 us): 581 cyc/step/SIMD = VALU 384 + MFMA 139 + stall 58.
// Closed levers (measured): trans floor 224 cyc/SIMD-step (5 exp2 + 2 rcp
// per state is exact-algebra minimal); MFMA 2 tiles/batch is the floor for
// <=4-batch A (denser A needs 4/8-wave barriers: R18 = +59 cyc, net 0);
// 2048 waves = 2/SIMD occupancy cap (1 state/lane); intra-wave dual-stream
// does not fill stalls (R19). Open: wall ~= 2x per-wave chain suggests the
// two cohabitant stranger waves run IN-PHASE (convoy) — MFMA+chain phases
// collide instead of dovetailing.
// R21:
//  1. Convoy-break: odd per-XCD blocks ((bid>>3)&1) s_sleep(5) (~320 cyc
//     ~ half step period) once before the loop -> anti-phases ~50% of
//     cohabitant pairs if convoyed. One-time tail cost ~0.1 us. Clean A/B.
//  2. fmaf folds: uv=fmaf(ea,vv,vv), s=fmaf(-ed,ww,ww), hd=fmaf(ee,pm,pm)
//     (-3 plain ops/state, same math); setprio(1) extended through the
//     4 chain-critical exp-arg adds.
// Everything else identical to R20/R17: parity pair u=2n+P, 4 MFMA tiles
// (tau=2g+P), dbuf LDS h exchange, rational acts with -L/-2L folded, zero
// extraction acc[g][0], 1024 blocks x 2 waves = 2 waves/SIMD.

#define HH 32
#define TT 1024
#define BPB 4               // batches per block (= per wave pair)
#define NT 128

typedef _Float16 half8 __attribute__((ext_vector_type(8)));
typedef float    f32x4 __attribute__((ext_vector_type(4)));

__global__ __attribute__((amdgpu_flat_work_group_size(NT, NT),
                          amdgpu_waves_per_eu(2, 2)))
void lstm_vp(const float* __restrict__ x,
             const float* __restrict__ W_ih,
             const float* __restrict__ W_hh,
             const float* __restrict__ b_ih,
             const float* __restrict__ b_hh,
             const float* __restrict__ fc_W,
             const float* __restrict__ fc_b,
             float* __restrict__ out)
{
    __shared__ _Float16 xw[BPB * TT];                 // 8 KB: x fp16
    __shared__ __align__(16) _Float16 hx[2][BPB][HH]; // 512 B: h dbuf
    __shared__ float fo[BPB];                         // epilogue partials

    const int tid  = threadIdx.x;
    const int P    = tid >> 6;           // wave parity: unit 2n+P
    const int lane = tid & 63;
    const int q    = lane >> 4;          // batch index within block (0..3)
    const int n    = lane & 15;          // unit-pair index (0..15)
    const int u    = 2 * n + P;          // owned unit
    const int gb0  = blockIdx.x * BPB;

    // ---- stage the block's 4 x-rows into LDS as fp16 (both waves) ----
    {
        const float4* xg = (const float4*)(x + (size_t)gb0 * TT);
        #pragma unroll
        for (int it = 0; it < (BPB * TT / 4) / NT; ++it) {
            const int idx = it * NT + tid;
            const float4 v = xg[idx];
            _Float16* dst = &xw[idx * 4];
            dst[0] = (_Float16)v.x; dst[1] = (_Float16)v.y;
            dst[2] = (_Float16)v.z; dst[3] = (_Float16)v.w;
        }
    }

    const float L1 = 1.4426950408889634f;    // log2(e)

    // ---- B-fragments: this wave's parity tiles only (tau = 2g+P).
    //      Col n = W_hh row 32g+2n+P; lane supplies B[k=8q+j][n].
    //      Pre-scaled by -L (i,f,o) / -2L (g). ----
    half8 wf[4];
    #pragma unroll
    for (int g = 0; g < 4; ++g) {
        const float s = (g == 2) ? -2.0f * L1 : -L1;
        const float* arow = W_hh + (size_t)(32 * g + 2 * n + P) * HH + 8 * q;
        #pragma unroll
        for (int j = 0; j < 8; ++j)
            wf[g][j] = (_Float16)(arow[j] * s);
    }

    // ---- per-lane act constants for the single owned unit u ----
    float wx[4], bb[4];
    #pragma unroll
    for (int g = 0; g < 4; ++g) {
        const float s = (g == 2) ? -2.0f * L1 : -L1;
        wx[g] = W_ih[g * HH + u] * s;
        bb[g] = (b_ih[g * HH + u] + b_hh[g * HH + u]) * s;
    }

    // zero h slot 0 (each lane covers its own state) + staging sync
    hx[0][q][u] = (_Float16)0.0f;
    __syncthreads();

    // ---- convoy-break: anti-phase ~50% of cohabitant stranger pairs ----
    if ((blockIdx.x >> 3) & 1)
        __builtin_amdgcn_s_sleep(5);     // ~320 cyc ~ half step period

    // A-frag read pointers: units 8q..8q+7 of batch n>>2 (16B, aligned)
    const half8* hr0 = (const half8*)&hx[0][n >> 2][8 * q];
    const half8* hr1 = (const half8*)&hx[1][n >> 2][8 * q];

    float c = 0.0f, h = 0.0f;

    const half8* xp = (const half8*)&xw[q * TT];
    half8 xcur = xp[0];

    #pragma unroll 1
    for (int tc = 0; tc < TT / 8; ++tc) {
        const half8 xv8 = xcur;
        xcur = xp[(tc + 1) & (TT / 8 - 1)];   // prefetch next chunk (off-chain)

        // pre-convert the chunk to f32 once (off the serial chain)
        float xf[8];
        #pragma unroll
        for (int j = 0; j < 8; ++j) xf[j] = (float)xv8[j];

        #pragma unroll
        for (int tt = 0; tt < 8; ++tt) {
            // ---- critical segment: read + MFMA + exp-args at high prio ----
            __builtin_amdgcn_s_setprio(1);

            // A-frag: one ds_read_b128 from current slot
            const half8 av = (tt & 1) ? *hr1 : *hr0;

            // preact input part, OFF the chain (fills ds_read shadow)
            const float xv = xf[tt];
            float qq[4];
            #pragma unroll
            for (int g = 0; g < 4; ++g)
                qq[g] = fmaf(xv, wx[g], bb[g]);

            const f32x4 zero = {0.0f, 0.0f, 0.0f, 0.0f};
            f32x4 acc[4];
            #pragma unroll
            for (int g = 0; g < 4; ++g) {
                acc[g] = __builtin_amdgcn_mfma_f32_16x16x32_f16(
                             av, wf[g], zero, 0, 0, 0);
                asm("" : "+v"(acc[g]));   // pin quad to arch VGPRs
            }

            // exp2 args, fixed element 0: zero extraction (chain-critical)
            const float ai = acc[0][0] + qq[0];
            const float af = acc[1][0] + qq[1];
            const float ag = acc[2][0] + qq[2];
            const float ao = acc[3][0] + qq[3];

            __builtin_amdgcn_s_setprio(0);

            const float ea = __builtin_amdgcn_exp2f(ai);  // e^-i
            const float eb = __builtin_amdgcn_exp2f(af);  // e^-f
            const float ed = __builtin_amdgcn_exp2f(ag);  // e^-2g
            const float ee = __builtin_amdgcn_exp2f(ao);  // e^-o

            // ---- c' = (c*u*v + w*(2-v)) / (u*v*w); fmaf-folded ----
            const float vv = 1.0f + ed;
            const float ww = 1.0f + eb;
            const float uv = fmaf(ea, vv, vv);            // (1+ea)*vv
            const float s  = fmaf(-ed, ww, ww);           // ww*(1-ed) = w*(2-v)
            const float num = fmaf(c, uv, s);
            const float den = uv * ww;
            const float tm  = num * (-2.0f * L1);   // off-chain, || with rcp
            const float rc  = __builtin_amdgcn_rcpf(den);
            c = num * rc;

            // ---- h = (1-m)/((1+e)(1+m)); marg fused ----
            const float marg = fminf(tm * rc, 126.0f);
            const float m  = __builtin_amdgcn_exp2f(marg);
            const float pm = 1.0f + m;
            const float hd = fmaf(ee, pm, pm);            // (1+ee)*(1+m)
            h = (1.0f - m) * __builtin_amdgcn_rcpf(hd);

            // ---- publish h for next step, flip slot, sync pair ----
            hx[(tt & 1) ^ 1][q][u] = (_Float16)h;
            __syncthreads();
        }
    }

    // ---- epilogue: out[gb0+q] = fc_W . h + fc_b across the wave pair ----
    float pr = h * fc_W[u];
    pr += __shfl_xor(pr, 1, 64);
    pr += __shfl_xor(pr, 2, 64);
    pr += __shfl_xor(pr, 4, 64);
    pr += __shfl_xor(pr, 8, 64);
    if (P == 1 && n == 0) fo[q] = pr;
    __syncthreads();
    if (P == 0 && n == 0)
        out[gb0 + q] = pr + fo[q] + fc_b[0];
}

extern "C" void kernel_launch(void* const* d_in, const int* in_sizes, int n_in,
                              void* d_out, int out_size, void* d_ws, size_t ws_size,
                              hipStream_t stream) {
    const float* x    = (const float*)d_in[0];
    const float* W_ih = (const float*)d_in[1];
    const float* W_hh = (const float*)d_in[2];
    const float* b_ih = (const float*)d_in[3];
    const float* b_hh = (const float*)d_in[4];
    const float* fc_W = (const float*)d_in[5];
    const float* fc_b = (const float*)d_in[6];
    float* out = (float*)d_out;

    const int B = in_sizes[0] / TT;   // 4096 (D == 1)
    dim3 grid(B / BPB), block(NT);
    lstm_vp<<<grid, block, 0, stream>>>(x, W_ih, W_hh, b_ih, b_hh,
                                        fc_W, fc_b, out);
}

// Round 10
// 279.337 us; speedup vs baseline: 1.0461x; 1.0461x over previous
//
#include <hip/hip_runtime.h>
#include <math.h>

// LSTM fused: H=32, D=1, B=4096, T=1024 — R22: R20 sched + fmaf folds + C-inject.
//
// R21 decomposition: folds cut busy (VALUBusy 66->60.5) but sleep +
// wide-setprio grew stall more (wall 248->254.5). Convoy hypothesis REFUTED;
// setprio must release right after the MFMA block (R20 scope) so the partner
// wave wins issue during this wave's act phase.
// R22 = R20 scheduling exactly + R21's fmaf folds + ONE new cut:
//   preact INJECTED AS MFMA C-OPERAND. mfma(A,B,C)=A*B+C and lane reads
//   acc[g][0] = (row 4q, col n) = exactly one C element. Persistent quad
//   cin[g]={qq[g],0,0,0} (zeros written once; D!=C so never clobbered),
//   cin[g][0]=fmaf(xv,wx,bb) runs off-chain -> the 4 serial acc+qq adds
//   vanish: chain is ds_read -> MFMA -> exp2. -4 plain ops, -~8 chain cyc,
//   +16 VGPR (88->~104, no occupancy change at 2 waves/SIMD).
// Ledger: R20 581 cyc/step = VALU 384 + MFMA 139 + stall 58. R22 target
// ~530-545 (VALU -35, stall -10). If >=246 us: roofline by exhaustion
// (occupancy cap, MFMA density, trans floor, barrier width, setprio, phase
// all measured closed).

#define HH 32
#define TT 1024
#define BPB 4               // batches per block (= per wave pair)
#define NT 128

typedef _Float16 half8 __attribute__((ext_vector_type(8)));
typedef float    f32x4 __attribute__((ext_vector_type(4)));

__global__ __attribute__((amdgpu_flat_work_group_size(NT, NT),
                          amdgpu_waves_per_eu(2, 2)))
void lstm_vp(const float* __restrict__ x,
             const float* __restrict__ W_ih,
             const float* __restrict__ W_hh,
             const float* __restrict__ b_ih,
             const float* __restrict__ b_hh,
             const float* __restrict__ fc_W,
             const float* __restrict__ fc_b,
             float* __restrict__ out)
{
    __shared__ _Float16 xw[BPB * TT];                 // 8 KB: x fp16
    __shared__ __align__(16) _Float16 hx[2][BPB][HH]; // 512 B: h dbuf
    __shared__ float fo[BPB];                         // epilogue partials

    const int tid  = threadIdx.x;
    const int P    = tid >> 6;           // wave parity: unit 2n+P
    const int lane = tid & 63;
    const int q    = lane >> 4;          // batch index within block (0..3)
    const int n    = lane & 15;          // unit-pair index (0..15)
    const int u    = 2 * n + P;          // owned unit
    const int gb0  = blockIdx.x * BPB;

    // ---- stage the block's 4 x-rows into LDS as fp16 (both waves) ----
    {
        const float4* xg = (const float4*)(x + (size_t)gb0 * TT);
        #pragma unroll
        for (int it = 0; it < (BPB * TT / 4) / NT; ++it) {
            const int idx = it * NT + tid;
            const float4 v = xg[idx];
            _Float16* dst = &xw[idx * 4];
            dst[0] = (_Float16)v.x; dst[1] = (_Float16)v.y;
            dst[2] = (_Float16)v.z; dst[3] = (_Float16)v.w;
        }
    }

    const float L1 = 1.4426950408889634f;    // log2(e)

    // ---- B-fragments: this wave's parity tiles only (tau = 2g+P).
    //      Col n = W_hh row 32g+2n+P; lane supplies B[k=8q+j][n].
    //      Pre-scaled by -L (i,f,o) / -2L (g). ----
    half8 wf[4];
    #pragma unroll
    for (int g = 0; g < 4; ++g) {
        const float s = (g == 2) ? -2.0f * L1 : -L1;
        const float* arow = W_hh + (size_t)(32 * g + 2 * n + P) * HH + 8 * q;
        #pragma unroll
        for (int j = 0; j < 8; ++j)
            wf[g][j] = (_Float16)(arow[j] * s);
    }

    // ---- per-lane act constants for the single owned unit u ----
    float wx[4], bb[4];
    #pragma unroll
    for (int g = 0; g < 4; ++g) {
        const float s = (g == 2) ? -2.0f * L1 : -L1;
        wx[g] = W_ih[g * HH + u] * s;
        bb[g] = (b_ih[g * HH + u] + b_hh[g * HH + u]) * s;
    }

    // zero h slot 0 (each lane covers its own state) + staging sync
    hx[0][q][u] = (_Float16)0.0f;
    __syncthreads();

    // A-frag read pointers: units 8q..8q+7 of batch n>>2 (16B, aligned)
    const half8* hr0 = (const half8*)&hx[0][n >> 2][8 * q];
    const half8* hr1 = (const half8*)&hx[1][n >> 2][8 * q];

    float c = 0.0f, h = 0.0f;

    // persistent C-operand quads: {preact, 0, 0, 0}; zeros never clobbered
    f32x4 cin[4];
    #pragma unroll
    for (int g = 0; g < 4; ++g) cin[g] = (f32x4){0.0f, 0.0f, 0.0f, 0.0f};

    const half8* xp = (const half8*)&xw[q * TT];
    half8 xcur = xp[0];

    #pragma unroll 1
    for (int tc = 0; tc < TT / 8; ++tc) {
        const half8 xv8 = xcur;
        xcur = xp[(tc + 1) & (TT / 8 - 1)];   // prefetch next chunk (off-chain)

        // pre-convert the chunk to f32 once (off the serial chain)
        float xf[8];
        #pragma unroll
        for (int j = 0; j < 8; ++j) xf[j] = (float)xv8[j];

        #pragma unroll
        for (int tt = 0; tt < 8; ++tt) {
            // ---- critical segment: read + MFMA at high prio (R20 scope) ----
            __builtin_amdgcn_s_setprio(1);

            // A-frag: one ds_read_b128 from current slot
            const half8 av = (tt & 1) ? *hr1 : *hr0;

            // preact -> C-operand elem 0, OFF the chain (fills ds_read shadow)
            const float xv = xf[tt];
            #pragma unroll
            for (int g = 0; g < 4; ++g)
                cin[g][0] = fmaf(xv, wx[g], bb[g]);

            f32x4 acc[4];
            #pragma unroll
            for (int g = 0; g < 4; ++g) {
                acc[g] = __builtin_amdgcn_mfma_f32_16x16x32_f16(
                             av, wf[g], cin[g], 0, 0, 0);
                asm("" : "+v"(acc[g]));   // pin quad to arch VGPRs
            }

            __builtin_amdgcn_s_setprio(0);

            // ---- exp2 directly off the MFMA output (preact already in) ----
            const float ea = __builtin_amdgcn_exp2f(acc[0][0]);  // e^-i
            const float eb = __builtin_amdgcn_exp2f(acc[1][0]);  // e^-f
            const float ed = __builtin_amdgcn_exp2f(acc[2][0]);  // e^-2g
            const float ee = __builtin_amdgcn_exp2f(acc[3][0]);  // e^-o

            // ---- c' = (c*u*v + w*(2-v)) / (u*v*w); fmaf-folded ----
            const float vv = 1.0f + ed;
            const float ww = 1.0f + eb;
            const float uv = fmaf(ea, vv, vv);            // (1+ea)*vv
            const float s  = fmaf(-ed, ww, ww);           // ww*(1-ed) = w*(2-v)
            const float num = fmaf(c, uv, s);
            const float den = uv * ww;
            const float tm  = num * (-2.0f * L1);   // off-chain, || with rcp
            const float rc  = __builtin_amdgcn_rcpf(den);
            c = num * rc;

            // ---- h = (1-m)/((1+e)(1+m)); marg fused ----
            const float marg = fminf(tm * rc, 126.0f);
            const float m  = __builtin_amdgcn_exp2f(marg);
            const float pm = 1.0f + m;
            const float hd = fmaf(ee, pm, pm);            // (1+ee)*(1+m)
            h = (1.0f - m) * __builtin_amdgcn_rcpf(hd);

            // ---- publish h for next step, flip slot, sync pair ----
            hx[(tt & 1) ^ 1][q][u] = (_Float16)h;
            __syncthreads();
        }
    }

    // ---- epilogue: out[gb0+q] = fc_W . h + fc_b across the wave pair ----
    float pr = h * fc_W[u];
    pr += __shfl_xor(pr, 1, 64);
    pr += __shfl_xor(pr, 2, 64);
    pr += __shfl_xor(pr, 4, 64);
    pr += __shfl_xor(pr, 8, 64);
    if (P == 1 && n == 0) fo[q] = pr;
    __syncthreads();
    if (P == 0 && n == 0)
        out[gb0 + q] = pr + fo[q] + fc_b[0];
}

extern "C" void kernel_launch(void* const* d_in, const int* in_sizes, int n_in,
                              void* d_out, int out_size, void* d_ws, size_t ws_size,
                              hipStream_t stream) {
    const float* x    = (const float*)d_in[0];
    const float* W_ih = (const float*)d_in[1];
    const float* W_hh = (const float*)d_in[2];
    const float* b_ih = (const float*)d_in[3];
    const float* b_hh = (const float*)d_in[4];
    const float* fc_W = (const float*)d_in[5];
    const float* fc_b = (const float*)d_in[6];
    float* out = (float*)d_out;

    const int B = in_sizes[0] / TT;   // 4096 (D == 1)
    dim3 grid(B / BPB), block(NT);
    lstm_vp<<<grid, block, 0, stream>>>(x, W_ih, W_hh, b_ih, b_hh,
                                        fc_W, fc_b, out);
}